// Round 1
// baseline (184.616 us; speedup 1.0000x reference)
//
#include <hip/hip_runtime.h>

// Problem constants (from reference)
#define BSZ 128
#define NPTS 16384
#define GL 48
#define GW 20
#define GH 18
#define NTOT (BSZ * NPTS)          // 2,097,152 points
#define BLOCK 256

__global__ __launch_bounds__(BLOCK) void trilinear_huber_kernel(
    const float* __restrict__ voxels,   // [B, GL, GW, GH]
    const float* __restrict__ pts,      // [B, N, 3]
    const float* __restrict__ hgt,      // [B, N]
    float* __restrict__ out)            // [1]
{
    const int p = blockIdx.x * BLOCK + threadIdx.x;   // point id, grid exactly covers NTOT
    const int b = p >> 14;                             // N = 16384 = 2^14
    const float* vb = voxels + (size_t)b * (GL * GW * GH);

    const float px = pts[3 * p + 0];
    const float py = pts[3 * p + 1];
    const float pz = pts[3 * p + 2];
    const float hg = hgt[p];

    // shift into grid frame
    const float x = px + 2.4f;          // LENGTH/2
    const float y = py + 1.0f;          // WIDTH/2
    const float z = pz + hg * 0.5f;

    const float xm = floorf(x / 0.1f);
    const float ym = floorf(y / 0.1f);
    const float zm = floorf(z / 0.1f);

    // trilinear weights: t = (x - xm*res)/res  (== (lx+1)/2 of the reference)
    const float tx = (x - xm * 0.1f) * 10.0f;
    const float ty = (y - ym * 0.1f) * 10.0f;
    const float tz = (z - zm * 0.1f) * 10.0f;
    const float sx = 1.0f - tx, sy = 1.0f - ty, sz = 1.0f - tz;

    // clamped integer corner indices
    const int xi0 = (int)fminf(fmaxf(xm,        0.0f), (float)(GL - 1));
    const int xi1 = (int)fminf(fmaxf(xm + 1.0f, 0.0f), (float)(GL - 1));
    const int yi0 = (int)fminf(fmaxf(ym,        0.0f), (float)(GW - 1));
    const int yi1 = (int)fminf(fmaxf(ym + 1.0f, 0.0f), (float)(GW - 1));
    const int zi0 = (int)fminf(fmaxf(zm,        0.0f), (float)(GH - 1));
    const int zi1 = (int)fminf(fmaxf(zm + 1.0f, 0.0f), (float)(GH - 1));

    const int ox0 = xi0 * (GW * GH);
    const int ox1 = xi1 * (GW * GH);
    const int oy0 = yi0 * GH;
    const int oy1 = yi1 * GH;

    const float v000 = vb[ox0 + oy0 + zi0];
    const float v001 = vb[ox0 + oy0 + zi1];
    const float v010 = vb[ox0 + oy1 + zi0];
    const float v011 = vb[ox0 + oy1 + zi1];
    const float v100 = vb[ox1 + oy0 + zi0];
    const float v101 = vb[ox1 + oy0 + zi1];
    const float v110 = vb[ox1 + oy1 + zi0];
    const float v111 = vb[ox1 + oy1 + zi1];

    const float sdf =
        v111 * (tx * ty * tz) + v110 * (tx * ty * sz) +
        v101 * (tx * sy * tz) + v100 * (tx * sy * sz) +
        v011 * (sx * ty * tz) + v010 * (sx * ty * sz) +
        v001 * (sx * sy * tz) + v000 * (sx * sy * sz);

    // Huber(delta=1), elementwise
    const float ax = fabsf(sdf);
    float loss = (ax < 1.0f) ? 0.5f * sdf * sdf : ax - 0.5f;

    // wave-64 shuffle reduction
    #pragma unroll
    for (int off = 32; off > 0; off >>= 1)
        loss += __shfl_down(loss, off, 64);

    __shared__ float wsum[BLOCK / 64];
    const int lane = threadIdx.x & 63;
    const int wid  = threadIdx.x >> 6;
    if (lane == 0) wsum[wid] = loss;
    __syncthreads();

    if (threadIdx.x == 0) {
        float bsum = wsum[0] + wsum[1] + wsum[2] + wsum[3];
        atomicAdd(out, bsum * (1.0f / (float)NTOT));
    }
}

extern "C" void kernel_launch(void* const* d_in, const int* in_sizes, int n_in,
                              void* d_out, int out_size, void* d_ws, size_t ws_size,
                              hipStream_t stream) {
    const float* voxels = (const float*)d_in[0];   // [B, 48, 20, 18]
    const float* pts    = (const float*)d_in[1];   // [B, N, 3]
    const float* hgt    = (const float*)d_in[2];   // [B, N]
    float* out = (float*)d_out;

    // d_out is poisoned to 0xAA before every timed replay — zero it in-graph.
    hipMemsetAsync(out, 0, sizeof(float), stream);

    trilinear_huber_kernel<<<NTOT / BLOCK, BLOCK, 0, stream>>>(voxels, pts, hgt, out);
}

// Round 2
// 92.571 us; speedup vs baseline: 1.9943x; 1.9943x over previous
//
#include <hip/hip_runtime.h>

// Problem constants (from reference)
#define BSZ 128
#define NPTS 16384
#define GL 48
#define GW 20
#define GH 18
#define VOX_PER_B (GL * GW * GH)       // 17280 floats = 67.5 KB
#define NTOT (BSZ * NPTS)              // 2,097,152 points
#define BLOCK 512
#define BLOCKS_PER_BATCH 2
#define PTS_PER_BLOCK (NPTS / BLOCKS_PER_BATCH)   // 8192
#define PTS_PER_THREAD (PTS_PER_BLOCK / BLOCK)    // 16

__global__ __launch_bounds__(BLOCK) void trilinear_huber_lds_kernel(
    const float* __restrict__ voxels,   // [B, GL, GW, GH]
    const float* __restrict__ pts,      // [B, N, 3]
    const float* __restrict__ hgt,      // [B, N]
    float* __restrict__ out)            // [1]
{
    __shared__ float vlds[VOX_PER_B];   // 67.5 KB — whole batch slice

    const int b    = blockIdx.x >> 1;           // batch id
    const int half = blockIdx.x & 1;            // which half of the batch's points
    const int tid  = threadIdx.x;

    // ---- Stage batch voxel slice into LDS (coalesced float4) ----
    const float4* vb4 = (const float4*)(voxels + (size_t)b * VOX_PER_B);
    float4* lds4 = (float4*)vlds;
    #pragma unroll 2
    for (int i = tid; i < VOX_PER_B / 4; i += BLOCK)   // 4320 float4s
        lds4[i] = vb4[i];
    __syncthreads();

    // ---- Process 16 points per thread ----
    const int pbase = b * NPTS + half * PTS_PER_BLOCK;  // first point of this block
    float acc = 0.0f;

    #pragma unroll 4
    for (int k = 0; k < PTS_PER_THREAD; ++k) {
        const int p = pbase + k * BLOCK + tid;          // coalesced across lanes

        const float px = pts[3 * p + 0];
        const float py = pts[3 * p + 1];
        const float pz = pts[3 * p + 2];
        const float hg = hgt[p];

        const float x = px + 2.4f;          // LENGTH/2
        const float y = py + 1.0f;          // WIDTH/2
        const float z = pz + hg * 0.5f;

        const float xm = floorf(x / 0.1f);
        const float ym = floorf(y / 0.1f);
        const float zm = floorf(z / 0.1f);

        const float tx = (x - xm * 0.1f) * 10.0f;
        const float ty = (y - ym * 0.1f) * 10.0f;
        const float tz = (z - zm * 0.1f) * 10.0f;
        const float sx = 1.0f - tx, sy = 1.0f - ty, sz = 1.0f - tz;

        const int xi0 = (int)fminf(fmaxf(xm,        0.0f), (float)(GL - 1));
        const int xi1 = (int)fminf(fmaxf(xm + 1.0f, 0.0f), (float)(GL - 1));
        const int yi0 = (int)fminf(fmaxf(ym,        0.0f), (float)(GW - 1));
        const int yi1 = (int)fminf(fmaxf(ym + 1.0f, 0.0f), (float)(GW - 1));
        const int zi0 = (int)fminf(fmaxf(zm,        0.0f), (float)(GH - 1));
        const int zi1 = (int)fminf(fmaxf(zm + 1.0f, 0.0f), (float)(GH - 1));

        const int ox0 = xi0 * (GW * GH);
        const int ox1 = xi1 * (GW * GH);
        const int oy0 = yi0 * GH;
        const int oy1 = yi1 * GH;

        const float v000 = vlds[ox0 + oy0 + zi0];
        const float v001 = vlds[ox0 + oy0 + zi1];
        const float v010 = vlds[ox0 + oy1 + zi0];
        const float v011 = vlds[ox0 + oy1 + zi1];
        const float v100 = vlds[ox1 + oy0 + zi0];
        const float v101 = vlds[ox1 + oy0 + zi1];
        const float v110 = vlds[ox1 + oy1 + zi0];
        const float v111 = vlds[ox1 + oy1 + zi1];

        const float sdf =
            v111 * (tx * ty * tz) + v110 * (tx * ty * sz) +
            v101 * (tx * sy * tz) + v100 * (tx * sy * sz) +
            v011 * (sx * ty * tz) + v010 * (sx * ty * sz) +
            v001 * (sx * sy * tz) + v000 * (sx * sy * sz);

        const float ax = fabsf(sdf);
        acc += (ax < 1.0f) ? 0.5f * sdf * sdf : ax - 0.5f;
    }

    // ---- wave-64 shuffle reduction, then block reduction, one atomic ----
    #pragma unroll
    for (int off = 32; off > 0; off >>= 1)
        acc += __shfl_down(acc, off, 64);

    __shared__ float wsum[BLOCK / 64];
    const int lane = tid & 63;
    const int wid  = tid >> 6;
    if (lane == 0) wsum[wid] = acc;
    __syncthreads();

    if (tid == 0) {
        float bsum = 0.0f;
        #pragma unroll
        for (int w = 0; w < BLOCK / 64; ++w) bsum += wsum[w];
        atomicAdd(out, bsum * (1.0f / (float)NTOT));
    }
}

extern "C" void kernel_launch(void* const* d_in, const int* in_sizes, int n_in,
                              void* d_out, int out_size, void* d_ws, size_t ws_size,
                              hipStream_t stream) {
    const float* voxels = (const float*)d_in[0];   // [B, 48, 20, 18]
    const float* pts    = (const float*)d_in[1];   // [B, N, 3]
    const float* hgt    = (const float*)d_in[2];   // [B, N]
    float* out = (float*)d_out;

    // d_out is poisoned to 0xAA before every timed replay — zero it in-graph.
    hipMemsetAsync(out, 0, sizeof(float), stream);

    trilinear_huber_lds_kernel<<<BSZ * BLOCKS_PER_BATCH, BLOCK, 0, stream>>>(
        voxels, pts, hgt, out);
}

// Round 3
// 88.346 us; speedup vs baseline: 2.0897x; 1.0478x over previous
//
#include <hip/hip_runtime.h>

// Problem constants (from reference)
#define BSZ 128
#define NPTS 16384
#define GL 48
#define GW 20
#define GH 18
#define VOX_PER_B (GL * GW * GH)       // 17280 floats = 67.5 KB
#define NTOT (BSZ * NPTS)              // 2,097,152 points
#define BLOCK 512
#define BLOCKS_PER_BATCH 4
#define NBLK (BSZ * BLOCKS_PER_BATCH)             // 512 blocks -> 2 blocks/CU, 16 waves
#define PTS_PER_BLOCK (NPTS / BLOCKS_PER_BATCH)   // 4096
#define GROUP_PTS 4                                // consecutive points per thread-group
#define GROUPS 2                                   // 512 thr * 4 pts * 2 = 4096

// One point's trilinear sample + huber. Math kept bit-identical to rounds 1-2
// (x/0.1f division, (x - xm*0.1f)*10.0f weights) which measured absmax 0.0.
__device__ __forceinline__ float point_loss(const float* __restrict__ vlds,
                                            float px, float py, float pz, float hg)
{
    const float x = px + 2.4f;          // LENGTH/2
    const float y = py + 1.0f;          // WIDTH/2
    const float z = pz + hg * 0.5f;

    const float xm = floorf(x / 0.1f);
    const float ym = floorf(y / 0.1f);
    const float zm = floorf(z / 0.1f);

    const float tx = (x - xm * 0.1f) * 10.0f;
    const float ty = (y - ym * 0.1f) * 10.0f;
    const float tz = (z - zm * 0.1f) * 10.0f;
    const float sx = 1.0f - tx, sy = 1.0f - ty, sz = 1.0f - tz;

    const int xi0 = (int)fminf(fmaxf(xm,        0.0f), (float)(GL - 1));
    const int xi1 = (int)fminf(fmaxf(xm + 1.0f, 0.0f), (float)(GL - 1));
    const int yi0 = (int)fminf(fmaxf(ym,        0.0f), (float)(GW - 1));
    const int yi1 = (int)fminf(fmaxf(ym + 1.0f, 0.0f), (float)(GW - 1));

    // z handled as an adjacent pair so each (x,y) corner-pair is ONE ds_read2_b32:
    //   base zb = clamp(zm, 0, GH-2); pair = {vlds[..+zb], vlds[..+zb+1]}
    //   zm >= GH-1  -> both corners clamp to GH-1 -> use pair[1] for the z0 corner
    //   zm < 0      -> both corners clamp to 0    -> use pair[0] for the z1 corner
    const int  zb   = (int)fminf(fmaxf(zm, 0.0f), (float)(GH - 2));
    const bool z_hi = (zm >= (float)(GH - 1));
    const bool z_lo = (zm < 0.0f);

    const int ox0 = xi0 * (GW * GH);
    const int ox1 = xi1 * (GW * GH);
    const int oy0 = yi0 * GH;
    const int oy1 = yi1 * GH;

    const float* q11 = vlds + (ox1 + oy1 + zb);
    const float* q10 = vlds + (ox1 + oy0 + zb);
    const float* q01 = vlds + (ox0 + oy1 + zb);
    const float* q00 = vlds + (ox0 + oy0 + zb);

    float a11 = q11[0], b11 = q11[1];
    float a10 = q10[0], b10 = q10[1];
    float a01 = q01[0], b01 = q01[1];
    float a00 = q00[0], b00 = q00[1];

    // select for clamped-z cases
    const float v110 = z_hi ? b11 : a11;  const float v111 = z_lo ? a11 : b11;
    const float v100 = z_hi ? b10 : a10;  const float v101 = z_lo ? a10 : b10;
    const float v010 = z_hi ? b01 : a01;  const float v011 = z_lo ? a01 : b01;
    const float v000 = z_hi ? b00 : a00;  const float v001 = z_lo ? a00 : b00;

    const float sdf =
        (tx * ty) * (tz * v111 + sz * v110) +
        (tx * sy) * (tz * v101 + sz * v100) +
        (sx * ty) * (tz * v011 + sz * v010) +
        (sx * sy) * (tz * v001 + sz * v000);

    const float ax = fabsf(sdf);
    return (ax < 1.0f) ? 0.5f * sdf * sdf : ax - 0.5f;
}

__global__ __launch_bounds__(BLOCK, 4) void trilinear_huber_lds_kernel(
    const float* __restrict__ voxels,   // [B, GL, GW, GH]
    const float* __restrict__ pts,      // [B, N, 3]
    const float* __restrict__ hgt,      // [B, N]
    float* __restrict__ out)            // [1]
{
    __shared__ float vlds[VOX_PER_B];   // 67.5 KB (2 blocks/CU fit in 160 KB)
    __shared__ float wsum[BLOCK / 64];

    // XCD swizzle: the 4 blocks of one batch share blockIdx%8 (same XCD) so the
    // voxel slice is HBM-fetched once and L2-served 3x. Pure perf heuristic.
    const int bid  = blockIdx.x;
    const int xcd  = bid & 7;
    const int rest = bid >> 3;          // [0, 64)
    const int slot = rest & 15;         // [0, 16)
    const int quar = rest >> 4;         // [0, 4)
    const int b    = xcd * 16 + slot;   // batch id [0, 128)
    const int tid  = threadIdx.x;

    // ---- Stage batch voxel slice into LDS (coalesced float4) ----
    const float4* vb4 = (const float4*)(voxels + (size_t)b * VOX_PER_B);
    float4* lds4 = (float4*)vlds;
    for (int i = tid; i < VOX_PER_B / 4; i += BLOCK)   // 4320 float4s
        lds4[i] = vb4[i];
    __syncthreads();

    // ---- Process 8 points per thread: 2 groups of 4 consecutive (float4 loads) ----
    const int pbase = b * NPTS + quar * PTS_PER_BLOCK;
    float acc = 0.0f;

    #pragma unroll
    for (int g = 0; g < GROUPS; ++g) {
        const int p0 = pbase + g * (BLOCK * GROUP_PTS) + tid * GROUP_PTS;

        const float4* pp = (const float4*)(pts + 3 * (size_t)p0);  // 48B, 16B-aligned
        const float4 f0 = pp[0];   // x0 y0 z0 x1
        const float4 f1 = pp[1];   // y1 z1 x2 y2
        const float4 f2 = pp[2];   // z2 x3 y3 z3
        const float4 hh = *(const float4*)(hgt + p0);

        acc += point_loss(vlds, f0.x, f0.y, f0.z, hh.x);
        acc += point_loss(vlds, f0.w, f1.x, f1.y, hh.y);
        acc += point_loss(vlds, f1.z, f1.w, f2.x, hh.z);
        acc += point_loss(vlds, f2.y, f2.z, f2.w, hh.w);
    }

    // ---- wave-64 shuffle reduction, then block reduction, one atomic ----
    #pragma unroll
    for (int off = 32; off > 0; off >>= 1)
        acc += __shfl_down(acc, off, 64);

    const int lane = tid & 63;
    const int wid  = tid >> 6;
    if (lane == 0) wsum[wid] = acc;
    __syncthreads();

    if (tid == 0) {
        float bsum = 0.0f;
        #pragma unroll
        for (int w = 0; w < BLOCK / 64; ++w) bsum += wsum[w];
        atomicAdd(out, bsum * (1.0f / (float)NTOT));
    }
}

extern "C" void kernel_launch(void* const* d_in, const int* in_sizes, int n_in,
                              void* d_out, int out_size, void* d_ws, size_t ws_size,
                              hipStream_t stream) {
    const float* voxels = (const float*)d_in[0];   // [B, 48, 20, 18]
    const float* pts    = (const float*)d_in[1];   // [B, N, 3]
    const float* hgt    = (const float*)d_in[2];   // [B, N]
    float* out = (float*)d_out;

    // d_out is poisoned to 0xAA before every timed replay — zero it in-graph.
    hipMemsetAsync(out, 0, sizeof(float), stream);

    trilinear_huber_lds_kernel<<<NBLK, BLOCK, 0, stream>>>(voxels, pts, hgt, out);
}